// Round 9
// baseline (2135.838 us; speedup 1.0000x reference)
//
#include <hip/hip_runtime.h>

typedef __attribute__((ext_vector_type(8))) short short8;      // 8 x bf16
typedef __attribute__((ext_vector_type(4))) float f32x4;
typedef __attribute__((ext_vector_type(4))) unsigned uint4v;

#define Bsz 4
#define Cin 256
#define Cout 256
#define Hh 64
#define Ww 64
#define HW 4096
#define NG 16
#define EPSV 1e-5f

#define CSTR 72   // col LDS row stride ushorts: 64 data + 8 pad (144 B)

static __device__ __forceinline__ unsigned f2bf(float f) {
    unsigned u = __float_as_uint(f);
    return (u + 0x7fffu + ((u >> 16) & 1u)) >> 16;   // RNE bf16
}
static __device__ __forceinline__ float bf2f(short s) {
    return __uint_as_float(((unsigned)(ushort)s) << 16);
}
// barrier that does NOT drain vmcnt: global prefetches stay in flight.
// LDS visibility only needs lgkmcnt(0).
static __device__ __forceinline__ void lgkm_barrier() {
    asm volatile("s_waitcnt lgkmcnt(0)\ns_barrier" ::: "memory");
}

// ---------------------------------------------------------------------------
// Kernel 0 (prep): blocks 0..1023: transpose in [b][c][y][x] -> bf16 in_t
//   [b][y][x][c]; blocks 1024..3327: weight reorder -> bf16 wtb[ks][o][32],
//   ks = (kk*256+c)/32; + zero GN stats.
// ---------------------------------------------------------------------------
__global__ void prep_kernel(const float* __restrict__ in, ushort* __restrict__ in_t,
                            const float* __restrict__ w, ushort* __restrict__ wtb,
                            float* __restrict__ stats) {
    const int t = threadIdx.x;
    if (blockIdx.x < 1024) {
        __shared__ float tile[64 * 68];
        const int bx = blockIdx.x;             // b*256 + y*4 + ct
        const int b  = bx >> 8;
        const int y  = (bx >> 2) & 63;
        const int c0 = (bx & 3) * 64;
        const int xr = (t & 15) * 4, cr = t >> 4;
#pragma unroll
        for (int j = 0; j < 4; j++) {
            const int c = cr + j * 16;
            const float4 v = *(const float4*)(in + ((size_t)(b * 256 + c0 + c)) * HW + y * 64 + xr);
            *(float4*)&tile[c * 68 + xr] = v;
        }
        __syncthreads();
        const int cw = (t & 15) * 4, xw = t >> 4;
#pragma unroll
        for (int j = 0; j < 4; j++) {
            const int x = xw + j * 16;
            unsigned long long pk =
                (unsigned long long)f2bf(tile[(cw + 0) * 68 + x])        |
                ((unsigned long long)f2bf(tile[(cw + 1) * 68 + x]) << 16)|
                ((unsigned long long)f2bf(tile[(cw + 2) * 68 + x]) << 32)|
                ((unsigned long long)f2bf(tile[(cw + 3) * 68 + x]) << 48);
            *(unsigned long long*)(in_t + ((size_t)(b * HW + y * 64 + x)) * 256 + c0 + cw) = pk;
        }
    } else {
        if (blockIdx.x == 1024 && t < 128) stats[t] = 0.f;
        const int i = (blockIdx.x - 1024) * 256 + t;    // over 589824
        if (i >= Cout * Cin * 9) return;
        const int o = i / (Cin * 9);
        const int rem = i % (Cin * 9);
        const int c = rem / 9, kk = rem % 9;
        const int ks = kk * 8 + (c >> 5);               // = (kk*256+c)>>5
        wtb[(ks * 256 + o) * 32 + (c & 31)] = (ushort)f2bf(w[i]);
    }
}

// ---------------------------------------------------------------------------
// Kernel 1: fused deformable sampling + bf16 MFMA conv + GN partial stats.
// Block: 512 thr (8 waves) = one row (b,h): N=64 px, M=256 Co. Grid 256.
// BK=64 super-steps (36). Gathers from bf16 pixel-major in_t: one corner's
// 64-ch slice = one 128B line; thread (px, cq) reads 4 x 16B coalesced.
// lgkm-only barriers: gather prefetch depth 2, A prefetch depth 1 stay in
// flight across the barrier (vmcnt never force-drained).
// ---------------------------------------------------------------------------
__launch_bounds__(512, 2)
__global__ void dcn_kernel(const ushort* __restrict__ in_t,
                           const float* __restrict__ offs,
                           const float* __restrict__ mask,
                           const ushort* __restrict__ wtb,
                           const float* __restrict__ bias,
                           float* __restrict__ out,
                           float* __restrict__ stats) {
    __shared__ ushort s_col[2][64 * CSTR];   // 18 KB double-buffered col tile
    __shared__ int2   s_ta[9 * 64];          // [k][px]: corner pixel idx (y*64+xb)
    __shared__ f32x4  s_tw[9 * 64];          // [k][px]: folded pair weights

    const int t  = threadIdx.x;
    const int bx = blockIdx.x;
    // XCD swizzle: XCD (bx&7) serves one (batch, h-half)
    const int q  = bx & 7, r = bx >> 3;
    const int b  = q >> 1;
    const int h  = ((q & 1) << 5) | r;
    const int lane = t & 63;
    const int wv   = t >> 6;                 // wave 0..7 (m-strip 32*wv)
    const int quad = lane >> 4;
    const int l15  = lane & 15;
    const int px   = t >> 3;                 // gather pixel 0..63
    const int cq   = t & 7;                  // gather channel octet (8 ch of 64)

    // ---- tap precompute: 9 kernel points x 64 pixels ----
    for (int j = t; j < 576; j += 512) {
        const int k = j >> 6, p = j & 63;
        const float* ob = offs + (size_t)b * 18 * HW + h * Ww + p;
        const float dy = ob[(2 * k) * HW];
        const float dx = ob[(2 * k + 1) * HW];
        const float m  = mask[((size_t)b * 9 + k) * HW + h * Ww + p];
        const float y = (float)h + (float)(k / 3 - 1) + dy;
        const float x = (float)p + (float)(k % 3 - 1) + dx;
        const float y0f = floorf(y), x0f = floorf(x);
        const float ly = y - y0f, lx = x - x0f;
        const float hy = 1.f - ly, hx = 1.f - lx;
        const int y0 = (int)y0f, x0 = (int)x0f;
        const int yc0 = min(max(y0, 0), 63);
        const int yc1 = min(max(y0 + 1, 0), 63);
        const int xb  = min(max(x0, 0), 62);
        float ax = 0.f, ay = 0.f;
        if (x0 == xb) {                       // x0 in [0,62]
            ax = hx; ay = lx;
        } else if (x0 < xb) {                 // x0 < 0
            ax = (x0 + 1 == 0) ? lx : 0.f;
        } else {                              // x0 > 62
            ay = (x0 == 63) ? hx : 0.f;       // x0>=64: both corners OOB
        }
        const float w0 = (y0 >= 0 && y0 < 64) ? m * hy : 0.f;
        const float w1 = (y0 + 1 >= 0 && y0 + 1 < 64) ? m * ly : 0.f;
        s_ta[j] = make_int2(yc0 * 64 + xb, yc1 * 64 + xb);
        s_tw[j] = (f32x4){w0 * ax, w0 * ay, w1 * ax, w1 * ay};
    }
    __syncthreads();                          // full barrier (once)

    f32x4 acc[2][4];
#pragma unroll
    for (int i = 0; i < 2; i++)
#pragma unroll
        for (int nt = 0; nt < 4; nt++) acc[i][nt] = (f32x4){0.f, 0.f, 0.f, 0.f};

    const ushort* base_t = in_t + (size_t)b * (HW * 256);

    // gather issue for super-step s (BK=64): tap kk=s>>2, ch range (s&3)*64,
    // this thread: 8 ch at cq*8. 4 corners x 16B, coalesced 128B/8-lane-group.
#define GISS(s, gg)                                                  \
    {                                                                \
        const int2 ad = s_ta[((s) >> 2) * 64 + px];                  \
        const int coff = ((s) & 3) * 64 + cq * 8;                    \
        const ushort* p00 = base_t + (size_t)ad.x * 256 + coff;      \
        const ushort* p10 = base_t + (size_t)ad.y * 256 + coff;     \
        gg[0] = *(const short8*)p00;                                 \
        gg[1] = *(const short8*)(p00 + 256);                         \
        gg[2] = *(const short8*)p10;                                 \
        gg[3] = *(const short8*)(p10 + 256);                         \
    }

    short8 g[2][4];
    GISS(0, g[0]);                            // prologue: steps 0,1
    GISS(1, g[1]);

    short8 a0c[2], a1c[2], a0n[2], a1n[2];
    const ushort* wpbase = wtb + ((size_t)(wv * 32 + l15)) * 32 + quad * 8;
#pragma unroll
    for (int kh = 0; kh < 2; kh++) {          // A prologue (ks = 0,1)
        a0c[kh] = *(const short8*)(wpbase + (size_t)kh * 8192);
        a1c[kh] = *(const short8*)(wpbase + (size_t)kh * 8192 + 16 * 32);
    }

    const int colw = px * CSTR + cq * 8;

#pragma unroll 1
    for (int s = 0; s < 36; s++) {
        const int pb = s & 1;
        // blend prefetched corners (issued at s-2) -> pack -> publish
        {
            const f32x4 tw = s_tw[(s >> 2) * 64 + px];
            float vv[8];
#pragma unroll
            for (int j = 0; j < 8; j++)
                vv[j] = tw[0] * bf2f(g[pb][0][j]) + tw[1] * bf2f(g[pb][1][j]) +
                        tw[2] * bf2f(g[pb][2][j]) + tw[3] * bf2f(g[pb][3][j]);
            uint4v pk;
#pragma unroll
            for (int j = 0; j < 4; j++)
                pk[j] = f2bf(vv[2 * j]) | (f2bf(vv[2 * j + 1]) << 16);
            *(uint4v*)&s_col[pb][colw] = pk;
        }
        lgkm_barrier();                       // LDS visible; vmcnt NOT drained

        if (s < 34) GISS(s + 2, g[pb]);       // gather prefetch (depth 2)
        if (s < 35) {                         // A prefetch (depth 1)
            const ushort* wpn = wpbase + (size_t)(s + 1) * 2 * 8192;
#pragma unroll
            for (int kh = 0; kh < 2; kh++) {
                a0n[kh] = *(const short8*)(wpn + (size_t)kh * 8192);
                a1n[kh] = *(const short8*)(wpn + (size_t)kh * 8192 + 16 * 32);
            }
        }

        // B-frags from LDS + 16 MFMA
#pragma unroll
        for (int kh = 0; kh < 2; kh++) {
#pragma unroll
            for (int nt = 0; nt < 4; nt++) {
                const short8 bfr = *(const short8*)&s_col[pb][(nt * 16 + l15) * CSTR +
                                                             kh * 32 + quad * 8];
                acc[0][nt] = __builtin_amdgcn_mfma_f32_16x16x32_bf16(a0c[kh], bfr, acc[0][nt], 0, 0, 0);
                acc[1][nt] = __builtin_amdgcn_mfma_f32_16x16x32_bf16(a1c[kh], bfr, acc[1][nt], 0, 0, 0);
            }
        }
#pragma unroll
        for (int kh = 0; kh < 2; kh++) {
            a0c[kh] = a0n[kh];
            a1c[kh] = a1n[kh];
        }
    }
#undef GISS

    // ---- epilogue: bias, store, GN partial stats ----
    float gs[2], gq[2];
#pragma unroll
    for (int i = 0; i < 2; i++) {
        float sgn = 0.f, qq = 0.f;
        const int ob = wv * 32 + i * 16 + quad * 4;
#pragma unroll
        for (int reg = 0; reg < 4; reg++) {
            const int o = ob + reg;
            const float bv = bias[o];
            float* op = out + ((size_t)(b * 256 + o)) * HW + h * Ww + l15;
#pragma unroll
            for (int nt = 0; nt < 4; nt++) {
                const float v = acc[i][nt][reg] + bv;
                op[nt * 16] = v;
                sgn += v;
                qq += v * v;
            }
        }
        gs[i] = sgn; gq[i] = qq;
    }
#pragma unroll
    for (int off = 32; off; off >>= 1) {
        gs[0] += __shfl_xor(gs[0], off);
        gq[0] += __shfl_xor(gq[0], off);
        gs[1] += __shfl_xor(gs[1], off);
        gq[1] += __shfl_xor(gq[1], off);
    }
    if (lane == 0) {
#pragma unroll
        for (int i = 0; i < 2; i++) {
            const int g2 = wv * 2 + i;
            atomicAdd(&stats[((size_t)b * NG + g2) * 2],     gs[i]);
            atomicAdd(&stats[((size_t)b * NG + g2) * 2 + 1], gq[i]);
        }
    }
}

// ---------------------------------------------------------------------------
// Kernel 2: GN apply (mu/rsqrt from accumulated sums, in place)
// ---------------------------------------------------------------------------
__global__ void gn_apply_kernel(float* __restrict__ x, const float* __restrict__ stats,
                                const float* __restrict__ gamma,
                                const float* __restrict__ beta) {
    const int i = blockIdx.x * 256 + threadIdx.x;      // float4 idx, 1048576 total
    const int plane = i >> 10;                         // b*256 + o
    const int o = plane & 255;
    const int bg = plane >> 4;                         // b*16 + g
    const float s = stats[bg * 2], qv = stats[bg * 2 + 1];
    const float inv_n = 1.f / 65536.f;
    const float mu = s * inv_n;
    const float var = qv * inv_n - mu * mu;
    const float rs = rsqrtf(var + EPSV);
    const float ga = gamma[o] * rs;
    const float be = beta[o] - mu * ga;
    float4 v = ((float4*)x)[i];
    v.x = v.x * ga + be;
    v.y = v.y * ga + be;
    v.z = v.z * ga + be;
    v.w = v.w * ga + be;
    ((float4*)x)[i] = v;
}

// ---------------------------------------------------------------------------
extern "C" void kernel_launch(void* const* d_in, const int* in_sizes, int n_in,
                              void* d_out, int out_size, void* d_ws, size_t ws_size,
                              hipStream_t stream) {
    const float* input  = (const float*)d_in[0];
    const float* offset = (const float*)d_in[1];
    const float* maskp  = (const float*)d_in[2];
    const float* weight = (const float*)d_in[3];
    const float* bias   = (const float*)d_in[4];
    const float* gamma  = (const float*)d_in[5];
    const float* beta   = (const float*)d_in[6];
    float* out = (float*)d_out;

    // ws: in_t bf16 (8.39 MB) | wtb bf16 (1.18 MB) | stats (512 B)
    ushort* in_t  = (ushort*)d_ws;
    ushort* wtb   = (ushort*)((char*)d_ws + (size_t)Bsz * HW * 256 * 2);
    float*  stats = (float*)((char*)wtb + (size_t)Cout * Cin * 9 * 2);

    hipLaunchKernelGGL(prep_kernel, dim3(1024 + 2304), dim3(256), 0, stream,
                       input, in_t, weight, wtb, stats);
    hipLaunchKernelGGL(dcn_kernel, dim3(Bsz * Hh), dim3(512), 0, stream,
                       in_t, offset, maskp, wtb, bias, out, stats);
    hipLaunchKernelGGL(gn_apply_kernel, dim3((Bsz * Cout * HW / 4) / 256), dim3(256), 0,
                       stream, out, stats, gamma, beta);
}